// Round 7
// baseline (11860.559 us; speedup 1.0000x reference)
//
#include <hip/hip_runtime.h>
#include <cstddef>

typedef unsigned short ushort_t;
typedef __attribute__((ext_vector_type(8))) short bhalf8;
typedef __attribute__((ext_vector_type(4))) unsigned short ushort4v;
typedef __attribute__((ext_vector_type(4))) float floatx4;

#define T_STEPS 63
#define GRID_N 224

__device__ __forceinline__ float bf2f(unsigned short u) {
  union { unsigned int i; float f; } c; c.i = ((unsigned int)u) << 16; return c.f;
}
__device__ __forceinline__ unsigned short f2bf(float f) {
  union { float f; unsigned int i; } c; c.f = f;
  unsigned int x = c.i;
  return (unsigned short)((x + 0x7FFFu + ((x >> 16) & 1u)) >> 16);
}
__device__ __forceinline__ float tanh_f(float x) {
  float e = exp2f(x * 2.8853900817779268f);
  return 1.f - 2.f / (e + 1.f);
}
__device__ __forceinline__ float sigm_f(float x) {
  return 1.f / (1.f + exp2f(x * -1.4426950408889634f));
}

// ---------------------------------------------------------------------------
// fp32 -> bf16 bulk conversion; n4 = element_count/4.
__global__ __launch_bounds__(256) void conv_k(const float* __restrict__ in,
                                              ushort_t* __restrict__ outp, int n4) {
  int g = blockIdx.x * 256 + threadIdx.x;
  if (g < n4) {
    floatx4 v = ((const floatx4*)in)[g];
    ushort4v o;
    o[0] = f2bf(v[0]); o[1] = f2bf(v[1]); o[2] = f2bf(v[2]); o[3] = f2bf(v[3]);
    ((ushort4v*)outp)[g] = o;
  }
}

// ---------------------------------------------------------------------------
// bsum = b_in + b_ctx (f32); vattbf = bf16(v_att); zero both barrier words.
__global__ __launch_bounds__(256) void bsum_k(const float* __restrict__ b_in,
    const float* __restrict__ b_ctx, const float* __restrict__ v_att,
    float* __restrict__ bsum, ushort_t* __restrict__ vattbf,
    unsigned* __restrict__ bar) {
  int i = blockIdx.x * 256 + threadIdx.x;
  if (i == 0) { bar[0] = 0u; bar[128] = 0u; }
  if (i < 1024) {
    bsum[i] = b_in[i] + b_ctx[i];
    vattbf[i] = f2bf(v_att[i]);
  }
}

// ---------------------------------------------------------------------------
// init h1/h2 (fp32 + bf16 mirror) from dec_init (NL,N,H) fp32. 65536 threads.
__global__ __launch_bounds__(256) void init_k(const float* __restrict__ dec_init,
    float* __restrict__ h1, float* __restrict__ h2,
    ushort_t* __restrict__ h1bf, ushort_t* __restrict__ h2bf) {
  int g = blockIdx.x * 256 + threadIdx.x;
  int l = g >> 15, idx = g & 32767;
  float f = dec_init[g];
  if (l == 0) { h1[idx] = f; h1bf[idx] = f2bf(f); }
  else        { h2[idx] = f; h2bf[idx] = f2bf(f); }
}

// ---------------------------------------------------------------------------
// encp[r,c] = dot(enc_hids[r,:], W_att_enc[c,:]) fp32 -> bf16. 2048x1024.
__global__ __launch_bounds__(256) void encp_s(const float* __restrict__ enc_hids,
    const float* __restrict__ Wae, ushort_t* __restrict__ encp) {
  int g = blockIdx.x * 256 + threadIdx.x;
  int r = g >> 10, c = g & 1023;
  const float* x = enc_hids + (size_t)r * 1024;
  const float* w = Wae + (size_t)c * 1024;
  float s = 0.f;
  for (int k = 0; k < 1024; k += 4) {
    floatx4 a = *(const floatx4*)(x + k);
    floatx4 b = *(const floatx4*)(w + k);
    s += a[0] * b[0] + a[1] * b[1] + a[2] * b[2] + a[3] * b[3];
  }
  encp[g] = f2bf(s);
}

// ---------------------------------------------------------------------------
// Shared 32-row x 32-col  C = X[32x1024] @ W^T tile (K=1024), 256 threads.
__device__ __forceinline__ void tile32(const ushort_t* __restrict__ Xs,
    const ushort_t* __restrict__ Wp, const float* __restrict__ bias,
    float* __restrict__ Co, int ldc, int colbase,
    ushort_t* sXk, ushort_t* sBk, int tid) {
  int wid = tid >> 6, lane = tid & 63;
  int klane = (lane >> 4) << 3;
  int nt = wid & 1, mt = wid >> 1;
  floatx4 acc = {0, 0, 0, 0};
  for (int kp = 0; kp < 4; ++kp) {
    __syncthreads();
    #pragma unroll
    for (int it = 0; it < 4; ++it) {
      int v = it * 256 + tid; int row = v >> 5, vc = v & 31;
      *(bhalf8*)(&sXk[row * 264 + vc * 8]) = *(const bhalf8*)(Xs + (size_t)row * 1024 + kp * 256 + vc * 8);
      *(bhalf8*)(&sBk[row * 264 + vc * 8]) = *(const bhalf8*)(Wp + (size_t)(colbase + row) * 1024 + kp * 256 + vc * 8);
    }
    __syncthreads();
    #pragma unroll
    for (int kit = 0; kit < 8; ++kit) {
      int k = kit * 32 + klane;
      bhalf8 a  = *(const bhalf8*)(&sXk[(mt * 16 + (lane & 15)) * 264 + k]);
      bhalf8 bf = *(const bhalf8*)(&sBk[(nt * 16 + (lane & 15)) * 264 + k]);
      acc = __builtin_amdgcn_mfma_f32_16x16x32_bf16(a, bf, acc, 0, 0, 0);
    }
  }
  int colw = colbase + nt * 16 + (lane & 15);
  float bv = bias ? bias[colw] : 0.f;
  int r0 = (lane >> 4) << 2;
  #pragma unroll
  for (int i = 0; i < 4; ++i)
    Co[(size_t)(mt * 16 + r0 + i) * ldc + colw] = acc[i] + bv;
}

// ---------------------------------------------------------------------------
// gh1 init: gh1 = h1bf @ Whh0^T + bhh0.  Grid 96 blocks.
__global__ __launch_bounds__(256) void ginit_k(const ushort_t* __restrict__ h1bf,
    const ushort_t* __restrict__ Whh, const float* __restrict__ bhh,
    float* __restrict__ gh1) {
  __shared__ __align__(16) ushort_t sXk[32 * 264];
  __shared__ __align__(16) ushort_t sBk[32 * 264];
  tile32(h1bf, Whh, bhh, gh1, 3072, blockIdx.x * 32, sXk, sBk, threadIdx.x);
}

// ---------------------------------------------------------------------------
struct PArgs {
  const float *enc_hids, *bhh, *bih, *emb_table, *bsum;
  const int* ids;
  const ushort_t *Whh, *Wih, *Wad, *Wctx, *Win, *encp, *vatt;
  float *h1, *h2, *dprj, *gh1, *gh2;
  ushort_t *h1bf, *h2bf, *ctxbf, *mctxbf;
  float *out_hid, *out_att, *out_prev;
  unsigned* bar;   // bar[0] = full barrier, bar[128] = mini (32-block) barrier
};

// Relaxed-spin barrier with backoff; cache ops only at entry/exit.
__device__ __forceinline__ void gbar_n(unsigned* bar, unsigned& ph, unsigned nblk) {
  __syncthreads();
  if (threadIdx.x == 0) {
    __threadfence();   // publish prior writes (agent scope: L2 writeback)
    __hip_atomic_fetch_add(bar, 1u, __ATOMIC_RELAXED, __HIP_MEMORY_SCOPE_AGENT);
    unsigned tgt = (++ph) * nblk;
    unsigned spins = 0;
    while (__hip_atomic_load(bar, __ATOMIC_RELAXED, __HIP_MEMORY_SCOPE_AGENT) < tgt) {
      if (spins < 8)       __builtin_amdgcn_s_sleep(2);   // 128 cyc
      else if (spins < 32) __builtin_amdgcn_s_sleep(16);  // 1024 cyc
      else                 __builtin_amdgcn_s_sleep(64);  // 4096 cyc
      if (++spins > (1u << 20)) break;  // ~1s: fail loudly, never in normal op
    }
    __threadfence();   // observe others' writes (agent scope: invalidate once)
  }
  __syncthreads();
}

// GRU layer body (128 blocks participate): gi = Xs @ Wg^T + add; gates -> h.
__device__ __forceinline__ void gru_body(int b, int tid,
    const ushort_t* __restrict__ Xs, const ushort_t* __restrict__ Wg,
    const float* __restrict__ gh, const float* __restrict__ hp,
    float* __restrict__ ho, ushort_t* __restrict__ hobf,
    const float* __restrict__ add, float* __restrict__ outh,
    ushort_t* sX16, float* sRed) {
  int wid = tid >> 6, lane = tid & 63;
  int mh = b & 1, g = b >> 1, j0 = g * 16;
  #pragma unroll
  for (int it = 0; it < 8; ++it) {
    int v = it * 256 + tid; int row = v >> 7, vc = v & 127;
    *(bhalf8*)(&sX16[row * 1032 + vc * 8]) = *(const bhalf8*)(Xs + (size_t)(mh * 16 + row) * 1024 + vc * 8);
  }
  __syncthreads();
  floatx4 a0 = {0,0,0,0}, a1 = {0,0,0,0}, a2 = {0,0,0,0};
  int klane = (lane >> 4) << 3;
  const ushort_t* Wr = Wg + (size_t)(j0 + (lane & 15)) * 1024;
  for (int kit = 0; kit < 8; ++kit) {
    int k = wid * 256 + kit * 32 + klane;
    bhalf8 a = *(const bhalf8*)(&sX16[(lane & 15) * 1032 + k]);
    a0 = __builtin_amdgcn_mfma_f32_16x16x32_bf16(a, *(const bhalf8*)(Wr + k), a0, 0, 0, 0);
    a1 = __builtin_amdgcn_mfma_f32_16x16x32_bf16(a, *(const bhalf8*)(Wr + 1048576 + k), a1, 0, 0, 0);
    a2 = __builtin_amdgcn_mfma_f32_16x16x32_bf16(a, *(const bhalf8*)(Wr + 2097152 + k), a2, 0, 0, 0);
  }
  if (wid) {
    ((floatx4*)sRed)[((wid - 1) * 3 + 0) * 64 + lane] = a0;
    ((floatx4*)sRed)[((wid - 1) * 3 + 1) * 64 + lane] = a1;
    ((floatx4*)sRed)[((wid - 1) * 3 + 2) * 64 + lane] = a2;
  }
  __syncthreads();
  if (wid == 0) {
    #pragma unroll
    for (int w = 0; w < 3; ++w) {
      a0 += ((floatx4*)sRed)[(w * 3 + 0) * 64 + lane];
      a1 += ((floatx4*)sRed)[(w * 3 + 1) * 64 + lane];
      a2 += ((floatx4*)sRed)[(w * 3 + 2) * 64 + lane];
    }
    int col = j0 + (lane & 15), r0 = (lane >> 4) << 2;
    #pragma unroll
    for (int i = 0; i < 4; ++i) {
      int n = mh * 16 + r0 + i;
      float ir  = a0[i] + add[col];
      float iz  = a1[i] + add[col + 1024];
      float inn = a2[i] + add[col + 2048];
      int gb = n * 3072 + col;
      float r = sigm_f(ir + gh[gb]);
      float z = sigm_f(iz + gh[gb + 1024]);
      float nn = tanh_f(inn + r * gh[gb + 2048]);
      float h = (1.f - z) * nn + z * hp[n * 1024 + col];
      ho[n * 1024 + col] = h;
      hobf[n * 1024 + col] = f2bf(h);
      if (outh) outh[(size_t)n * 64512 + col] = h;
    }
  }
}

// ---------------------------------------------------------------------------
__global__ __launch_bounds__(256) void decoder_pers(PArgs A) {
  // LDS union: tiles (2x 32x264 bf16 = 33792B) | gru (16x1032 bf16 + 2304 f32)
  __shared__ __align__(16) unsigned char smemU[42240];
  __shared__ float sSc[64];
  __shared__ float sAtt[64];
  __shared__ int sIds[32];
  ushort_t* sXk  = (ushort_t*)smemU;
  ushort_t* sBk  = (ushort_t*)(smemU + 16896);
  ushort_t* sX16 = (ushort_t*)smemU;
  float*    sRed = (float*)(smemU + 33024);

  const int b = blockIdx.x, tid = threadIdx.x;
  unsigned ph = 0, phm = 0;
  unsigned* barF = A.bar;
  unsigned* barM = A.bar + 128;

  for (int t = 0; t < T_STEPS; ++t) {
    // ---- S0: dprj (32 blk) | gh2 (96 blk) ----
    if (b < 32)        tile32(A.h2bf, A.Wad, nullptr, A.dprj, 1024, b * 32, sXk, sBk, tid);
    else if (b < 128)  tile32(A.h2bf, A.Whh + 3145728, A.bhh + 3072, A.gh2, 3072, (b - 32) * 32, sXk, sBk, tid);
    gbar_n(barF, ph, GRID_N);

    // ---- S1: attention (32 blk) -> minibar -> mctx (32 blk) ----
    if (b < 32) {
      int n = b;
      int l = tid >> 2, q = tid & 3;
      const ushort_t* ep = A.encp + ((size_t)(n * 64 + l)) * 1024 + q * 256;
      const float*    dp = A.dprj + n * 1024 + q * 256;
      float p = 0.f;
      for (int it = 0; it < 32; ++it) {
        bhalf8 E = *(const bhalf8*)(ep + it * 8);
        bhalf8 V = *(const bhalf8*)(A.vatt + q * 256 + it * 8);
        #pragma unroll
        for (int r = 0; r < 8; ++r)
          p += tanh_f(bf2f((unsigned short)E[r]) + dp[it * 8 + r]) * bf2f((unsigned short)V[r]);
      }
      p += __shfl_down(p, 1, 4);
      p += __shfl_down(p, 2, 4);
      if (q == 0) sSc[l] = p;
      __syncthreads();
      if (tid < 64) {
        float s = sSc[tid];
        float m = s;
        for (int off = 32; off; off >>= 1) m = fmaxf(m, __shfl_xor(m, off));
        float e = exp2f((s - m) * 1.4426950408889634f);
        float sum = e;
        for (int off = 32; off; off >>= 1) sum += __shfl_xor(sum, off);
        float a = e / sum;
        sAtt[tid] = a;
        A.out_att[(size_t)n * 4032 + tid * 63 + t] = a;
      }
      __syncthreads();
      const float* er = A.enc_hids + ((size_t)n * 64) * 1024 + tid * 4;
      float c0 = 0, c1 = 0, c2 = 0, c3 = 0;
      for (int l2 = 0; l2 < 64; ++l2) {
        floatx4 ev = *(const floatx4*)(er + (size_t)l2 * 1024);
        float a = sAtt[l2];
        c0 += a * ev[0]; c1 += a * ev[1]; c2 += a * ev[2]; c3 += a * ev[3];
      }
      ushort_t* cp = A.ctxbf + n * 1024 + tid * 4;
      cp[0] = f2bf(c0); cp[1] = f2bf(c1); cp[2] = f2bf(c2); cp[3] = f2bf(c3);

      // mini-barrier among blocks 0..31 only
      gbar_n(barM, phm, 32);

      // mctx = ctx @ Wctx^T + emb_t @ Win^T + bsum
      int colbase = b * 32;
      if (tid < 32) sIds[tid] = A.ids[tid * 64 + t];
      __syncthreads();
      int wid = tid >> 6, lane = tid & 63;
      int klane = (lane >> 4) << 3;
      int nt = wid & 1, mt = wid >> 1;
      floatx4 acc = {0, 0, 0, 0};
      for (int kp = 0; kp < 4; ++kp) {
        // phase A: ctx chunk + Wctx chunk
        __syncthreads();
        #pragma unroll
        for (int it = 0; it < 4; ++it) {
          int v = it * 256 + tid; int row = v >> 5, vc = v & 31;
          *(bhalf8*)(&sXk[row * 264 + vc * 8]) = *(const bhalf8*)(A.ctxbf + (size_t)row * 1024 + kp * 256 + vc * 8);
          *(bhalf8*)(&sBk[row * 264 + vc * 8]) = *(const bhalf8*)(A.Wctx + (size_t)(colbase + row) * 1024 + kp * 256 + vc * 8);
        }
        __syncthreads();
        #pragma unroll
        for (int kit = 0; kit < 8; ++kit) {
          int k = kit * 32 + klane;
          bhalf8 a  = *(const bhalf8*)(&sXk[(mt * 16 + (lane & 15)) * 264 + k]);
          bhalf8 bf = *(const bhalf8*)(&sBk[(nt * 16 + (lane & 15)) * 264 + k]);
          acc = __builtin_amdgcn_mfma_f32_16x16x32_bf16(a, bf, acc, 0, 0, 0);
        }
        // phase B: emb chunk (fp32 gather -> bf16) + Win chunk
        __syncthreads();
        #pragma unroll
        for (int it = 0; it < 4; ++it) {
          int v = it * 256 + tid; int row = v >> 5, vc = v & 31;
          const float* epp = A.emb_table + (size_t)sIds[row] * 1024 + kp * 256 + vc * 8;
          floatx4 f0 = *(const floatx4*)epp;
          floatx4 f1 = *(const floatx4*)(epp + 4);
          bhalf8 o;
          o[0] = (short)f2bf(f0[0]); o[1] = (short)f2bf(f0[1]);
          o[2] = (short)f2bf(f0[2]); o[3] = (short)f2bf(f0[3]);
          o[4] = (short)f2bf(f1[0]); o[5] = (short)f2bf(f1[1]);
          o[6] = (short)f2bf(f1[2]); o[7] = (short)f2bf(f1[3]);
          *(bhalf8*)(&sXk[row * 264 + vc * 8]) = o;
          *(bhalf8*)(&sBk[row * 264 + vc * 8]) = *(const bhalf8*)(A.Win + (size_t)(colbase + row) * 1024 + kp * 256 + vc * 8);
        }
        __syncthreads();
        #pragma unroll
        for (int kit = 0; kit < 8; ++kit) {
          int k = kit * 32 + klane;
          bhalf8 a  = *(const bhalf8*)(&sXk[(mt * 16 + (lane & 15)) * 264 + k]);
          bhalf8 bf = *(const bhalf8*)(&sBk[(nt * 16 + (lane & 15)) * 264 + k]);
          acc = __builtin_amdgcn_mfma_f32_16x16x32_bf16(a, bf, acc, 0, 0, 0);
        }
      }
      int colw = colbase + nt * 16 + (lane & 15);
      int r0 = (lane >> 4) << 2;
      #pragma unroll
      for (int i = 0; i < 4; ++i) {
        int row = mt * 16 + r0 + i;
        A.mctxbf[(size_t)row * 1024 + colw] = f2bf(acc[i] + A.bsum[colw]);
      }
    }
    gbar_n(barF, ph, GRID_N);

    // ---- S2: GRU layer 1 (128 blk) ----
    if (b < 128)
      gru_body(b, tid, A.mctxbf, A.Wih, A.gh1, A.h1, A.h1, A.h1bf,
               A.bih, nullptr, sX16, sRed);
    gbar_n(barF, ph, GRID_N);

    // ---- S3: GRU layer 2 (128 blk) | gh1 for t+1 (96 blk) ----
    if (b < 128)
      gru_body(b, tid, A.h1bf, A.Wih + 3145728, A.gh2, A.h2, A.h2, A.h2bf,
               A.bih + 3072, A.out_hid + (size_t)t * 1024, sX16, sRed);
    else
      tile32(A.h1bf, A.Whh, A.bhh, A.gh1, 3072, (b - 128) * 32, sXk, sBk, tid);
    gbar_n(barF, ph, GRID_N);
  }

  // ---- final: out_prev (NL,N,H) ----
  if (b < 64) {
    int l = b >> 5, n = b & 31;
    const float* src = l ? A.h2 : A.h1;
    float* dst = A.out_prev + (size_t)l * 32768 + n * 1024;
    for (int c = tid; c < 1024; c += 256) dst[c] = src[n * 1024 + c];
  }
}

// ---------------------------------------------------------------------------
extern "C" void kernel_launch(void* const* d_in, const int* in_sizes, int n_in,
                              void* d_out, int out_size, void* d_ws, size_t ws_size,
                              hipStream_t stream) {
  const int*   input_ids = (const int*)d_in[0];
  const float* dec_init  = (const float*)d_in[1];
  const float* enc_hids  = (const float*)d_in[2];
  const float* emb_table = (const float*)d_in[3];
  const float* W_in      = (const float*)d_in[4];
  const float* b_in      = (const float*)d_in[5];
  const float* W_ctx     = (const float*)d_in[6];
  const float* b_ctx     = (const float*)d_in[7];
  const float* W_att_dec = (const float*)d_in[8];
  const float* W_att_enc = (const float*)d_in[9];
  const float* v_att     = (const float*)d_in[10];
  const float* W_ih      = (const float*)d_in[11];
  const float* W_hh      = (const float*)d_in[12];
  const float* b_ih      = (const float*)d_in[13];
  const float* b_hh      = (const float*)d_in[14];
  (void)in_sizes; (void)n_in; (void)out_size;

  // ---- workspace layout (bytes), total 37,105,664 (~35.4 MB) ----
  const size_t WS_NEEDED = 37105664;
  if (ws_size < WS_NEEDED) return;
  char* ws = (char*)d_ws;
  float*    h1      = (float*)   (ws + 0);         // 131072
  float*    h2      = (float*)   (ws + 131072);    // 131072
  ushort_t* h1bf    = (ushort_t*)(ws + 262144);    // 65536
  ushort_t* h2bf    = (ushort_t*)(ws + 327680);    // 65536
  ushort_t* ctxbf   = (ushort_t*)(ws + 393216);    // 65536
  ushort_t* mctxbf  = (ushort_t*)(ws + 458752);    // 65536
  float*    dprj    = (float*)   (ws + 524288);    // 131072
  float*    gh1     = (float*)   (ws + 655360);    // 393216
  float*    gh2     = (float*)   (ws + 1048576);   // 393216
  float*    bsum    = (float*)   (ws + 1441792);   // 4096
  ushort_t* vattbf  = (ushort_t*)(ws + 1445888);   // 4096 (2048 + pad)
  unsigned* bar     = (unsigned*)(ws + 1449984);   // 4096 (bar[0] full, bar[128] mini)
  ushort_t* encp    = (ushort_t*)(ws + 1454080);   // 4194304  (2048x1024)
  ushort_t* Win_bf  = (ushort_t*)(ws + 5648384);   // 2097152
  ushort_t* Wctx_bf = (ushort_t*)(ws + 7745536);   // 2097152
  ushort_t* Wad_bf  = (ushort_t*)(ws + 9842688);   // 2097152
  ushort_t* Whh_bf  = (ushort_t*)(ws + 11939840);  // 12582912 (2x3072x1024)
  ushort_t* Wih_bf  = (ushort_t*)(ws + 24522752);  // 12582912 (2x3072x1024)

  float* out_hid  = (float*)d_out;            // (32, 63, 1024)
  float* out_att  = out_hid + 2064384;        // (32, 64, 63)
  float* out_prev = out_att + 129024;         // (2, 32, 1024)

  // -------- precompute (9 launches) --------
  bsum_k<<<dim3(4), dim3(256), 0, stream>>>(b_in, b_ctx, v_att, bsum, vattbf, bar);
  init_k<<<dim3(256), dim3(256), 0, stream>>>(dec_init, h1, h2, h1bf, h2bf);
  conv_k<<<dim3(6144), dim3(256), 0, stream>>>(W_hh, Whh_bf, 1572864);
  conv_k<<<dim3(6144), dim3(256), 0, stream>>>(W_ih, Wih_bf, 1572864);
  conv_k<<<dim3(1024), dim3(256), 0, stream>>>(W_att_dec, Wad_bf, 262144);
  conv_k<<<dim3(1024), dim3(256), 0, stream>>>(W_ctx, Wctx_bf, 262144);
  conv_k<<<dim3(1024), dim3(256), 0, stream>>>(W_in, Win_bf, 262144);
  encp_s<<<dim3(8192), dim3(256), 0, stream>>>(enc_hids, W_att_enc, encp);
  ginit_k<<<dim3(96), dim3(256), 0, stream>>>(h1bf, Whh_bf, b_hh, gh1);

  // -------- persistent decoder: 63 steps x (4 full + 1 mini) barriers --------
  PArgs A;
  A.enc_hids = enc_hids; A.bhh = b_hh; A.bih = b_ih; A.emb_table = emb_table;
  A.bsum = bsum; A.ids = input_ids;
  A.Whh = Whh_bf; A.Wih = Wih_bf; A.Wad = Wad_bf; A.Wctx = Wctx_bf; A.Win = Win_bf;
  A.encp = encp; A.vatt = vattbf;
  A.h1 = h1; A.h2 = h2; A.dprj = dprj; A.gh1 = gh1; A.gh2 = gh2;
  A.h1bf = h1bf; A.h2bf = h2bf; A.ctxbf = ctxbf; A.mctxbf = mctxbf;
  A.out_hid = out_hid; A.out_att = out_att; A.out_prev = out_prev;
  A.bar = bar;
  decoder_pers<<<dim3(GRID_N), dim3(256), 0, stream>>>(A);
}